// Round 2
// baseline (669.101 us; speedup 1.0000x reference)
//
#include <hip/hip_runtime.h>
#include <hip/hip_bf16.h>
#include <hip/hip_fp16.h>

typedef __attribute__((ext_vector_type(4))) float f32x4;
typedef __attribute__((ext_vector_type(8))) __bf16 bf16x8;
typedef __attribute__((ext_vector_type(4))) __bf16 bf16x4;
typedef __attribute__((ext_vector_type(8))) _Float16 f16x8;
typedef __attribute__((ext_vector_type(4))) int i32x4;

#define B_   8
#define S_   1024
#define H_   20
#define D_   64
#define E_   1280
#define QKV_ 3840
#define T_   8192

// ---------------- int32 -> bf16 convert (values in [-127,127], exact) ----------------
__global__ __launch_bounds__(256) void cvt_kernel(const int* __restrict__ in,
                                                  __bf16* __restrict__ out, int n4) {
    int i = blockIdx.x * 256 + threadIdx.x;
    if (i >= n4) return;
    i32x4 v = ((const i32x4*)in)[i];
    bf16x4 o;
    o[0] = (__bf16)(float)v[0];
    o[1] = (__bf16)(float)v[1];
    o[2] = (__bf16)(float)v[2];
    o[3] = (__bf16)(float)v[3];
    ((bf16x4*)out)[i] = o;
}

// ---------------- bf16 GEMM: C[M,N] = A[M,K] * B[N,K]^T, fused dequant epilogue -------
// epilogue 0: scatter q/k (fp16 hi+lo) and v (fp16, transposed to [B,H,D,S])
// epilogue 1: write fp32 to out
__global__ __launch_bounds__(256) void gemm_kernel(
    const __bf16* __restrict__ A, const __bf16* __restrict__ Bw,
    int M, int N, int K,
    const float* __restrict__ rowscale, const float* __restrict__ colscale,
    const float* __restrict__ bias, int epilogue,
    __half* __restrict__ qh_out, __half* __restrict__ ql_out,
    __half* __restrict__ kh_out, __half* __restrict__ kl_out,
    __half* __restrict__ vt_out, float* __restrict__ out)
{
    __shared__ __bf16 As[128 * 32];
    __shared__ __bf16 Bs[128 * 32];

    const int tid  = threadIdx.x;
    const int lane = tid & 63;
    const int wave = tid >> 6;
    const int wm = wave >> 1, wn = wave & 1;          // 2x2 waves of 64x64
    const int nTn = N >> 7;
    const int tm = blockIdx.x / nTn, tn = blockIdx.x % nTn;

    f32x4 acc[4][4] = {};

    // staging geometry: thread covers 16B (8 bf16)
    const int r0 = tid >> 2;
    const int ks = (tid & 3) * 8;
    const size_t abase = (size_t)tm * 128 * K;
    const size_t bbase = (size_t)tn * 128 * K;

    const int fr = lane & 15;
    const int fc = (lane >> 4) * 8;

    for (int k0 = 0; k0 < K; k0 += 32) {
        bf16x8 a0 = *(const bf16x8*)&A [abase + (size_t)r0        * K + k0 + ks];
        bf16x8 a1 = *(const bf16x8*)&A [abase + (size_t)(r0 + 64) * K + k0 + ks];
        bf16x8 b0 = *(const bf16x8*)&Bw[bbase + (size_t)r0        * K + k0 + ks];
        bf16x8 b1 = *(const bf16x8*)&Bw[bbase + (size_t)(r0 + 64) * K + k0 + ks];
        __syncthreads();   // protect previous iteration's frag reads
        *(bf16x8*)&As[(size_t)tid * 8]         = a0;
        *(bf16x8*)&As[(size_t)(tid + 256) * 8] = a1;
        *(bf16x8*)&Bs[(size_t)tid * 8]         = b0;
        *(bf16x8*)&Bs[(size_t)(tid + 256) * 8] = b1;
        __syncthreads();

        bf16x8 af[4], bf[4];
#pragma unroll
        for (int m = 0; m < 4; ++m)
            af[m] = *(const bf16x8*)&As[(wm * 64 + m * 16 + fr) * 32 + fc];
#pragma unroll
        for (int n = 0; n < 4; ++n)
            bf[n] = *(const bf16x8*)&Bs[(wn * 64 + n * 16 + fr) * 32 + fc];
#pragma unroll
        for (int m = 0; m < 4; ++m)
#pragma unroll
            for (int n = 0; n < 4; ++n)
                acc[m][n] = __builtin_amdgcn_mfma_f32_16x16x32_bf16(af[m], bf[n], acc[m][n], 0, 0, 0);
    }

    // epilogue: C row = tm*128 + wm*64 + m*16 + (lane>>4)*4 + r ; col = tn*128 + wn*64 + n*16 + (lane&15)
#pragma unroll
    for (int m = 0; m < 4; ++m) {
#pragma unroll
        for (int r = 0; r < 4; ++r) {
            const int grow = tm * 128 + wm * 64 + m * 16 + (lane >> 4) * 4 + r;
            const float rs = rowscale[grow];
#pragma unroll
            for (int n = 0; n < 4; ++n) {
                const int gcol = tn * 128 + wn * 64 + n * 16 + (lane & 15);
                const float v = acc[m][n][r] * (rs * colscale[gcol]) + bias[gcol];
                if (epilogue == 0) {
                    const int b = grow >> 10, s = grow & 1023;
                    if (gcol < 2 * E_) {
                        // q or k: store fp16 hi + fp16 residual (score precision)
                        const __half vh = (__half)v;
                        const __half vl = (__half)(v - (float)vh);
                        if (gcol < E_) {
                            const int h = gcol >> 6, d = gcol & 63;
                            const size_t idx = (((size_t)(b * H_ + h) << 10) + s) * 64 + d;
                            qh_out[idx] = vh; ql_out[idx] = vl;
                        } else {
                            const int o = gcol - E_, h = o >> 6, d = o & 63;
                            const size_t idx = (((size_t)(b * H_ + h) << 10) + s) * 64 + d;
                            kh_out[idx] = vh; kl_out[idx] = vl;
                        }
                    } else {
                        const int o = gcol - 2 * E_, h = o >> 6, d = o & 63;
                        vt_out[(((size_t)(b * H_ + h) * 64 + d) << 10) + s] = (__half)v;
                    }
                } else {
                    out[(size_t)grow * E_ + gcol] = v;
                }
            }
        }
    }
}

// ---------------- flash attention: split-fp16 QK^T, fp16 PV, online softmax ----------
// grid: (B*H) * (S/64); 4 waves/block, each wave owns 16 q-rows
__global__ __launch_bounds__(256) void attn_kernel(
    const __half* __restrict__ Qh, const __half* __restrict__ Ql,
    const __half* __restrict__ Kh, const __half* __restrict__ Kl,
    const __half* __restrict__ VT, __half* __restrict__ attn)
{
    __shared__ __half Pl[4 * 16 * 32];
    const int tid = threadIdx.x, lane = tid & 63, wave = tid >> 6;
    const int bh = blockIdx.x >> 4;          // b*H + h
    const int qt = blockIdx.x & 15;
    const int b = bh / H_, h = bh % H_;
    const int q0 = qt * 64 + wave * 16;
    const size_t base_sd = (size_t)bh * S_ * D_;
    const size_t base_ds = (size_t)bh * D_ * S_;
    const int fr = lane & 15, fg = lane >> 4;

    f16x8 qh0 = *(const f16x8*)&Qh[base_sd + (size_t)(q0 + fr) * 64 +      fg * 8];
    f16x8 qh1 = *(const f16x8*)&Qh[base_sd + (size_t)(q0 + fr) * 64 + 32 + fg * 8];
    f16x8 ql0 = *(const f16x8*)&Ql[base_sd + (size_t)(q0 + fr) * 64 +      fg * 8];
    f16x8 ql1 = *(const f16x8*)&Ql[base_sd + (size_t)(q0 + fr) * 64 + 32 + fg * 8];

    f32x4 o[4] = {};
    float mrow[4], lrow[4];
#pragma unroll
    for (int r = 0; r < 4; ++r) { mrow[r] = -INFINITY; lrow[r] = 0.f; }

    __half* Pw = &Pl[wave * 512];

    for (int kt = 0; kt < S_; kt += 32) {
        f32x4 s0 = {0.f, 0.f, 0.f, 0.f}, s1 = {0.f, 0.f, 0.f, 0.f};
        {
            const size_t r00 = base_sd + (size_t)(kt + fr) * 64;
            const size_t r10 = base_sd + (size_t)(kt + 16 + fr) * 64;
            f16x8 kh00 = *(const f16x8*)&Kh[r00 +      fg * 8];
            f16x8 kh01 = *(const f16x8*)&Kh[r00 + 32 + fg * 8];
            f16x8 kh10 = *(const f16x8*)&Kh[r10 +      fg * 8];
            f16x8 kh11 = *(const f16x8*)&Kh[r10 + 32 + fg * 8];
            f16x8 kl00 = *(const f16x8*)&Kl[r00 +      fg * 8];
            f16x8 kl01 = *(const f16x8*)&Kl[r00 + 32 + fg * 8];
            f16x8 kl10 = *(const f16x8*)&Kl[r10 +      fg * 8];
            f16x8 kl11 = *(const f16x8*)&Kl[r10 + 32 + fg * 8];
            s0 = __builtin_amdgcn_mfma_f32_16x16x32_f16(qh0, kh00, s0, 0, 0, 0);
            s0 = __builtin_amdgcn_mfma_f32_16x16x32_f16(qh1, kh01, s0, 0, 0, 0);
            s0 = __builtin_amdgcn_mfma_f32_16x16x32_f16(qh0, kl00, s0, 0, 0, 0);
            s0 = __builtin_amdgcn_mfma_f32_16x16x32_f16(qh1, kl01, s0, 0, 0, 0);
            s0 = __builtin_amdgcn_mfma_f32_16x16x32_f16(ql0, kh00, s0, 0, 0, 0);
            s0 = __builtin_amdgcn_mfma_f32_16x16x32_f16(ql1, kh01, s0, 0, 0, 0);
            s1 = __builtin_amdgcn_mfma_f32_16x16x32_f16(qh0, kh10, s1, 0, 0, 0);
            s1 = __builtin_amdgcn_mfma_f32_16x16x32_f16(qh1, kh11, s1, 0, 0, 0);
            s1 = __builtin_amdgcn_mfma_f32_16x16x32_f16(qh0, kl10, s1, 0, 0, 0);
            s1 = __builtin_amdgcn_mfma_f32_16x16x32_f16(qh1, kl11, s1, 0, 0, 0);
            s1 = __builtin_amdgcn_mfma_f32_16x16x32_f16(ql0, kh10, s1, 0, 0, 0);
            s1 = __builtin_amdgcn_mfma_f32_16x16x32_f16(ql1, kh11, s1, 0, 0, 0);
        }
        float p0[4], p1[4], fsc[4];
#pragma unroll
        for (int r = 0; r < 4; ++r) {
            s0[r] *= 0.125f; s1[r] *= 0.125f;
            float v = fmaxf(s0[r], s1[r]);
            v = fmaxf(v, __shfl_xor(v, 1));
            v = fmaxf(v, __shfl_xor(v, 2));
            v = fmaxf(v, __shfl_xor(v, 4));
            v = fmaxf(v, __shfl_xor(v, 8));
            const float mn = fmaxf(mrow[r], v);
            fsc[r] = __expf(mrow[r] - mn);      // exp(-inf)=0 on first tile
            mrow[r] = mn;
            p0[r] = __expf(s0[r] - mn);
            p1[r] = __expf(s1[r] - mn);
            float rsum = p0[r] + p1[r];
            rsum += __shfl_xor(rsum, 1);
            rsum += __shfl_xor(rsum, 2);
            rsum += __shfl_xor(rsum, 4);
            rsum += __shfl_xor(rsum, 8);
            lrow[r] = lrow[r] * fsc[r] + rsum;
        }
#pragma unroll
        for (int dc = 0; dc < 4; ++dc)
#pragma unroll
            for (int r = 0; r < 4; ++r) o[dc][r] *= fsc[r];

        // P (16x32 fp16) -> per-wave LDS, then re-read in A-frag layout
#pragma unroll
        for (int r = 0; r < 4; ++r) {
            Pw[(fg * 4 + r) * 32 + fr]      = (__half)p0[r];
            Pw[(fg * 4 + r) * 32 + 16 + fr] = (__half)p1[r];
        }
        asm volatile("s_waitcnt lgkmcnt(0)" ::: "memory");
        __builtin_amdgcn_sched_barrier(0);
        f16x8 pf = *(const f16x8*)&Pw[fr * 32 + fg * 8];
#pragma unroll
        for (int dc = 0; dc < 4; ++dc) {
            f16x8 vf = *(const f16x8*)&VT[base_ds + (size_t)(dc * 16 + fr) * S_ + kt + fg * 8];
            o[dc] = __builtin_amdgcn_mfma_f32_16x16x32_f16(pf, vf, o[dc], 0, 0, 0);
        }
        asm volatile("s_waitcnt lgkmcnt(0)" ::: "memory");  // P reads done before next overwrite
        __builtin_amdgcn_sched_barrier(0);
    }

#pragma unroll
    for (int dc = 0; dc < 4; ++dc)
#pragma unroll
        for (int r = 0; r < 4; ++r) {
            const int t = (b << 10) + q0 + fg * 4 + r;
            attn[(size_t)t * E_ + h * 64 + dc * 16 + fr] = (__half)(o[dc][r] / lrow[r]);
        }
}

// ---------------- per-token symmetric int8 requant (output as exact bf16) -------------
__global__ __launch_bounds__(256) void requant_kernel(
    const __half* __restrict__ attn, __bf16* __restrict__ aq, float* __restrict__ as_)
{
    const int t = blockIdx.x;
    const int tid = threadIdx.x;
    __shared__ float red[4];
    const __half* row = attn + (size_t)t * E_;
    float x[5];
    float amax = 0.f;
#pragma unroll
    for (int j = 0; j < 5; ++j) {
        x[j] = (float)row[tid + j * 256];
        amax = fmaxf(amax, fabsf(x[j]));
    }
#pragma unroll
    for (int off = 1; off < 64; off <<= 1) amax = fmaxf(amax, __shfl_xor(amax, off));
    if ((tid & 63) == 0) red[tid >> 6] = amax;
    __syncthreads();
    amax = fmaxf(fmaxf(red[0], red[1]), fmaxf(red[2], red[3]));
    const float s = fmaxf(amax / 127.f, 1e-8f);
    if (tid == 0) as_[t] = s;
#pragma unroll
    for (int j = 0; j < 5; ++j) {
        float qv = fminf(fmaxf(rintf(x[j] / s), -127.f), 127.f);
        aq[(size_t)t * E_ + tid + j * 256] = (__bf16)qv;
    }
}

// ---------------- launch ----------------
extern "C" void kernel_launch(void* const* d_in, const int* in_sizes, int n_in,
                              void* d_out, int out_size, void* d_ws, size_t ws_size,
                              hipStream_t stream) {
    const int*   x_q         = (const int*)d_in[0];
    const float* in_scale    = (const float*)d_in[1];
    const int*   w_qkv       = (const int*)d_in[2];
    const float* w_qkv_scale = (const float*)d_in[3];
    const float* b_qkv       = (const float*)d_in[4];
    const int*   w_out       = (const int*)d_in[5];
    const float* w_out_scale = (const float*)d_in[6];
    const float* b_out       = (const float*)d_in[7];
    float* out = (float*)d_out;

    char* ws = (char*)d_ws;
    // phase-1 buffers (dead after QKV GEMM / attention; reused later)
    __bf16* x_bf    = (__bf16*)(ws);                    // 20971520 B
    __bf16* wqkv_bf = (__bf16*)(ws + 20971520);         //  9830400 B
    __bf16* wout_bf = (__bf16*)(ws + 30801920);         //  3276800 B (live till GEMM2)
    __half* qh_f    = (__half*)(ws + 34078720);         // 20971520 B [B,H,S,D]
    __half* ql_f    = (__half*)(ws + 55050240);         // 20971520 B
    __half* kh_f    = (__half*)(ws + 76021760);         // 20971520 B
    __half* kl_f    = (__half*)(ws + 96993280);         // 20971520 B
    __half* vt_f    = (__half*)(ws + 117964800);        // 20971520 B [B,H,D,S]
    // reuse: attn overlays x_bf; aq overlays qh; a_s overlays wqkv
    __half* attn_f  = (__half*)(ws);                    // 20971520 B [T,E]
    __bf16* aq_bf   = (__bf16*)(ws + 34078720);         // 20971520 B [T,E]
    float*  a_s     = (float*) (ws + 20971520);         //    32768 B

    cvt_kernel<<<(T_ * E_ / 4 + 255) / 256, 256, 0, stream>>>(x_q, x_bf, T_ * E_ / 4);
    cvt_kernel<<<(QKV_ * E_ / 4 + 255) / 256, 256, 0, stream>>>(w_qkv, wqkv_bf, QKV_ * E_ / 4);
    cvt_kernel<<<(E_ * E_ / 4 + 255) / 256, 256, 0, stream>>>(w_out, wout_bf, E_ * E_ / 4);

    gemm_kernel<<<(T_ / 128) * (QKV_ / 128), 256, 0, stream>>>(
        x_bf, wqkv_bf, T_, QKV_, E_, in_scale, w_qkv_scale, b_qkv, 0,
        qh_f, ql_f, kh_f, kl_f, vt_f, nullptr);

    attn_kernel<<<B_ * H_ * (S_ / 64), 256, 0, stream>>>(qh_f, ql_f, kh_f, kl_f, vt_f, attn_f);

    requant_kernel<<<T_, 256, 0, stream>>>(attn_f, aq_bf, a_s);

    gemm_kernel<<<(T_ / 128) * (E_ / 128), 256, 0, stream>>>(
        aq_bf, wout_bf, T_, E_, E_, a_s, w_out_scale, b_out, 1,
        nullptr, nullptr, nullptr, nullptr, nullptr, out);
}

// Round 4
// 650.847 us; speedup vs baseline: 1.0280x; 1.0280x over previous
//
#include <hip/hip_runtime.h>
#include <hip/hip_bf16.h>
#include <hip/hip_fp16.h>

typedef __attribute__((ext_vector_type(4))) float f32x4;
typedef __attribute__((ext_vector_type(8))) __bf16 bf16x8;
typedef __attribute__((ext_vector_type(4))) __bf16 bf16x4;
typedef __attribute__((ext_vector_type(8))) _Float16 f16x8;
typedef __attribute__((ext_vector_type(4))) int i32x4;

#define B_   8
#define S_   1024
#define H_   20
#define D_   64
#define E_   1280
#define QKV_ 3840
#define T_   8192

#define EXP2F(x) __builtin_amdgcn_exp2f(x)

__device__ __forceinline__ void gload_lds16(const void* g, void* l) {
    __builtin_amdgcn_global_load_lds((const __attribute__((address_space(1))) int*)g,
                                     (__attribute__((address_space(3))) int*)l, 16, 0, 0);
}

// ---------------- int32 -> bf16 convert (values in [-127,127], exact) ----------------
__global__ __launch_bounds__(256) void cvt_kernel(const int* __restrict__ in,
                                                  __bf16* __restrict__ out, int n4) {
    int i = blockIdx.x * 256 + threadIdx.x;
    if (i >= n4) return;
    i32x4 v = ((const i32x4*)in)[i];
    bf16x4 o;
    o[0] = (__bf16)(float)v[0];
    o[1] = (__bf16)(float)v[1];
    o[2] = (__bf16)(float)v[2];
    o[3] = (__bf16)(float)v[3];
    ((bf16x4*)out)[i] = o;
}

// ---------------- bf16 GEMM: C[M,N] = A[M,K] * B[N,K]^T, fused dequant epilogue -------
// staging via global_load_lds width-16 (m97 2-barrier structure)
__global__ __launch_bounds__(256) void gemm_kernel(
    const __bf16* __restrict__ A, const __bf16* __restrict__ Bw,
    int M, int N, int K,
    const float* __restrict__ rowscale, const float* __restrict__ colscale,
    const float* __restrict__ bias, int epilogue,
    __half* __restrict__ qh_out, __half* __restrict__ ql_out,
    __half* __restrict__ kh_out, __half* __restrict__ kl_out,
    __half* __restrict__ vt_out, float* __restrict__ out)
{
    __shared__ __bf16 As[128 * 32];
    __shared__ __bf16 Bs[128 * 32];

    const int tid  = threadIdx.x;
    const int lane = tid & 63;
    const int wave = tid >> 6;
    const int wm = wave >> 1, wn = wave & 1;          // 2x2 waves of 64x64
    const int nTn = N >> 7;
    const int tm = blockIdx.x / nTn, tn = blockIdx.x % nTn;

    f32x4 acc[4][4] = {};

    const int r0 = tid >> 2;                // staging row
    const int ks = (tid & 3) * 8;           // staging k-offset (8 bf16 = 16B)
    const size_t abase = (size_t)tm * 128 * K;
    const size_t bbase = (size_t)tn * 128 * K;

    const int fr = lane & 15;
    const int fc = (lane >> 4) * 8;

    for (int k0 = 0; k0 < K; k0 += 32) {
        __syncthreads();   // previous iteration's frag reads complete before overwrite
        gload_lds16(&A [abase + (size_t)r0        * K + k0 + ks], &As[(size_t)tid * 8]);
        gload_lds16(&A [abase + (size_t)(r0 + 64) * K + k0 + ks], &As[(size_t)(tid + 256) * 8]);
        gload_lds16(&Bw[bbase + (size_t)r0        * K + k0 + ks], &Bs[(size_t)tid * 8]);
        gload_lds16(&Bw[bbase + (size_t)(r0 + 64) * K + k0 + ks], &Bs[(size_t)(tid + 256) * 8]);
        __syncthreads();   // staging complete (compiler drains vmcnt before barrier)

        bf16x8 af[4], bf[4];
#pragma unroll
        for (int m = 0; m < 4; ++m)
            af[m] = *(const bf16x8*)&As[(wm * 64 + m * 16 + fr) * 32 + fc];
#pragma unroll
        for (int n = 0; n < 4; ++n)
            bf[n] = *(const bf16x8*)&Bs[(wn * 64 + n * 16 + fr) * 32 + fc];
        __builtin_amdgcn_s_setprio(1);
#pragma unroll
        for (int m = 0; m < 4; ++m)
#pragma unroll
            for (int n = 0; n < 4; ++n)
                acc[m][n] = __builtin_amdgcn_mfma_f32_16x16x32_bf16(af[m], bf[n], acc[m][n], 0, 0, 0);
        __builtin_amdgcn_s_setprio(0);
    }

    // epilogue: C row = tm*128 + wm*64 + m*16 + (lane>>4)*4 + r ; col = tn*128 + wn*64 + n*16 + (lane&15)
#pragma unroll
    for (int m = 0; m < 4; ++m) {
#pragma unroll
        for (int r = 0; r < 4; ++r) {
            const int grow = tm * 128 + wm * 64 + m * 16 + (lane >> 4) * 4 + r;
            const float rs = rowscale[grow];
#pragma unroll
            for (int n = 0; n < 4; ++n) {
                const int gcol = tn * 128 + wn * 64 + n * 16 + (lane & 15);
                const float v = acc[m][n][r] * (rs * colscale[gcol]) + bias[gcol];
                if (epilogue == 0) {
                    const int b = grow >> 10, s = grow & 1023;
                    if (gcol < 2 * E_) {
                        const __half vh = (__half)v;
                        const __half vl = (__half)(v - (float)vh);
                        if (gcol < E_) {
                            const int h = gcol >> 6, d = gcol & 63;
                            const size_t idx = (((size_t)(b * H_ + h) << 10) + s) * 64 + d;
                            qh_out[idx] = vh; ql_out[idx] = vl;
                        } else {
                            const int o = gcol - E_, h = o >> 6, d = o & 63;
                            const size_t idx = (((size_t)(b * H_ + h) << 10) + s) * 64 + d;
                            kh_out[idx] = vh; kl_out[idx] = vl;
                        }
                    } else {
                        const int o = gcol - 2 * E_, h = o >> 6, d = o & 63;
                        vt_out[(((size_t)(b * H_ + h) * 64 + d) << 10) + s] = (__half)v;
                    }
                } else {
                    out[(size_t)grow * E_ + gcol] = v;
                }
            }
        }
    }
}

// ---------------- flash attention: split-fp16 QK^T, fp16 PV, online softmax ----------
// grid: (B*H) * (S/64); 4 waves/block, each wave owns 16 q-rows.
// Register double-buffered K prefetch (named A/B sets - no runtime-indexed frag arrays).
#define PSTRIDE 36   // padded P row stride (halfs)

#define LOADK(P, KT) do {                                                     \
    const size_t r00_ = base_sd + (size_t)((KT) + fr) * 64;                   \
    const size_t r10_ = base_sd + (size_t)((KT) + 16 + fr) * 64;              \
    P##h00 = *(const f16x8*)&Kh[r00_ +      fg * 8];                          \
    P##h01 = *(const f16x8*)&Kh[r00_ + 32 + fg * 8];                          \
    P##h10 = *(const f16x8*)&Kh[r10_ +      fg * 8];                          \
    P##h11 = *(const f16x8*)&Kh[r10_ + 32 + fg * 8];                          \
    P##l00 = *(const f16x8*)&Kl[r00_ +      fg * 8];                          \
    P##l01 = *(const f16x8*)&Kl[r00_ + 32 + fg * 8];                          \
    P##l10 = *(const f16x8*)&Kl[r10_ +      fg * 8];                          \
    P##l11 = *(const f16x8*)&Kl[r10_ + 32 + fg * 8];                          \
} while (0)

#define PROCESS(P, KT) do {                                                   \
    /* VT loads issued first: in flight across QK + softmax */                \
    const size_t vb_ = base_ds + (size_t)(KT) + fg * 8;                       \
    f16x8 vf0 = *(const f16x8*)&VT[vb_ + (size_t)(fr)      * S_];             \
    f16x8 vf1 = *(const f16x8*)&VT[vb_ + (size_t)(16 + fr) * S_];             \
    f16x8 vf2 = *(const f16x8*)&VT[vb_ + (size_t)(32 + fr) * S_];             \
    f16x8 vf3 = *(const f16x8*)&VT[vb_ + (size_t)(48 + fr) * S_];             \
    f32x4 s0 = {0.f, 0.f, 0.f, 0.f}, s1 = {0.f, 0.f, 0.f, 0.f};              \
    __builtin_amdgcn_s_setprio(1);                                            \
    s0 = __builtin_amdgcn_mfma_f32_16x16x32_f16(qh0, P##h00, s0, 0, 0, 0);    \
    s0 = __builtin_amdgcn_mfma_f32_16x16x32_f16(qh1, P##h01, s0, 0, 0, 0);    \
    s0 = __builtin_amdgcn_mfma_f32_16x16x32_f16(qh0, P##l00, s0, 0, 0, 0);    \
    s0 = __builtin_amdgcn_mfma_f32_16x16x32_f16(qh1, P##l01, s0, 0, 0, 0);    \
    s0 = __builtin_amdgcn_mfma_f32_16x16x32_f16(ql0, P##h00, s0, 0, 0, 0);    \
    s0 = __builtin_amdgcn_mfma_f32_16x16x32_f16(ql1, P##h01, s0, 0, 0, 0);    \
    s1 = __builtin_amdgcn_mfma_f32_16x16x32_f16(qh0, P##h10, s1, 0, 0, 0);    \
    s1 = __builtin_amdgcn_mfma_f32_16x16x32_f16(qh1, P##h11, s1, 0, 0, 0);    \
    s1 = __builtin_amdgcn_mfma_f32_16x16x32_f16(qh0, P##l10, s1, 0, 0, 0);    \
    s1 = __builtin_amdgcn_mfma_f32_16x16x32_f16(qh1, P##l11, s1, 0, 0, 0);    \
    s1 = __builtin_amdgcn_mfma_f32_16x16x32_f16(ql0, P##h10, s1, 0, 0, 0);    \
    s1 = __builtin_amdgcn_mfma_f32_16x16x32_f16(ql1, P##h11, s1, 0, 0, 0);    \
    __builtin_amdgcn_s_setprio(0);                                            \
    float p0[4], p1[4], fsc[4];                                               \
    _Pragma("unroll")                                                         \
    for (int r = 0; r < 4; ++r) {                                             \
        s0[r] *= 0.1803368801111204f;  /* 0.125 * log2(e) */                  \
        s1[r] *= 0.1803368801111204f;                                         \
        float v = fmaxf(s0[r], s1[r]);                                        \
        v = fmaxf(v, __shfl_xor(v, 1));                                       \
        v = fmaxf(v, __shfl_xor(v, 2));                                       \
        v = fmaxf(v, __shfl_xor(v, 4));                                       \
        v = fmaxf(v, __shfl_xor(v, 8));                                       \
        const float mn = fmaxf(mrow[r], v);                                   \
        fsc[r] = EXP2F(mrow[r] - mn);                                         \
        mrow[r] = mn;                                                         \
        p0[r] = EXP2F(s0[r] - mn);                                            \
        p1[r] = EXP2F(s1[r] - mn);                                            \
        float rsum = p0[r] + p1[r];                                           \
        rsum += __shfl_xor(rsum, 1);                                          \
        rsum += __shfl_xor(rsum, 2);                                          \
        rsum += __shfl_xor(rsum, 4);                                          \
        rsum += __shfl_xor(rsum, 8);                                          \
        lrow[r] = lrow[r] * fsc[r] + rsum;                                    \
    }                                                                         \
    _Pragma("unroll")                                                         \
    for (int dc = 0; dc < 4; ++dc)                                            \
        _Pragma("unroll")                                                     \
        for (int r = 0; r < 4; ++r) o[dc][r] *= fsc[r];                       \
    _Pragma("unroll")                                                         \
    for (int r = 0; r < 4; ++r) {                                             \
        Pw[(fg * 4 + r) * PSTRIDE + fr]      = (__half)p0[r];                 \
        Pw[(fg * 4 + r) * PSTRIDE + 16 + fr] = (__half)p1[r];                 \
    }                                                                         \
    asm volatile("s_waitcnt lgkmcnt(0)" ::: "memory");                        \
    __builtin_amdgcn_sched_barrier(0);                                        \
    f16x8 pf = *(const f16x8*)&Pw[fr * PSTRIDE + fg * 8];                     \
    __builtin_amdgcn_s_setprio(1);                                            \
    o[0] = __builtin_amdgcn_mfma_f32_16x16x32_f16(pf, vf0, o[0], 0, 0, 0);    \
    o[1] = __builtin_amdgcn_mfma_f32_16x16x32_f16(pf, vf1, o[1], 0, 0, 0);    \
    o[2] = __builtin_amdgcn_mfma_f32_16x16x32_f16(pf, vf2, o[2], 0, 0, 0);    \
    o[3] = __builtin_amdgcn_mfma_f32_16x16x32_f16(pf, vf3, o[3], 0, 0, 0);    \
    __builtin_amdgcn_s_setprio(0);                                            \
    asm volatile("s_waitcnt lgkmcnt(0)" ::: "memory");                        \
    __builtin_amdgcn_sched_barrier(0);                                        \
} while (0)

__global__ __launch_bounds__(256) void attn_kernel(
    const __half* __restrict__ Qh, const __half* __restrict__ Ql,
    const __half* __restrict__ Kh, const __half* __restrict__ Kl,
    const __half* __restrict__ VT, __half* __restrict__ attn)
{
    __shared__ __half Pl[4 * 16 * PSTRIDE];
    const int tid = threadIdx.x, lane = tid & 63, wave = tid >> 6;
    const int bh = blockIdx.x >> 4;          // b*H + h
    const int qt = blockIdx.x & 15;
    const int b = bh / H_, h = bh % H_;
    const int q0 = qt * 64 + wave * 16;
    const size_t base_sd = (size_t)bh * S_ * D_;
    const size_t base_ds = (size_t)bh * D_ * S_;
    const int fr = lane & 15, fg = lane >> 4;

    f16x8 qh0 = *(const f16x8*)&Qh[base_sd + (size_t)(q0 + fr) * 64 +      fg * 8];
    f16x8 qh1 = *(const f16x8*)&Qh[base_sd + (size_t)(q0 + fr) * 64 + 32 + fg * 8];
    f16x8 ql0 = *(const f16x8*)&Ql[base_sd + (size_t)(q0 + fr) * 64 +      fg * 8];
    f16x8 ql1 = *(const f16x8*)&Ql[base_sd + (size_t)(q0 + fr) * 64 + 32 + fg * 8];

    f32x4 o[4] = {};
    float mrow[4], lrow[4];
#pragma unroll
    for (int r = 0; r < 4; ++r) { mrow[r] = -INFINITY; lrow[r] = 0.f; }

    __half* Pw = &Pl[wave * 16 * PSTRIDE];

    f16x8 ah00, ah01, ah10, ah11, al00, al01, al10, al11;
    f16x8 bh00, bh01, bh10, bh11, bl00, bl01, bl10, bl11;

    LOADK(a, 0);
    for (int kt = 0; kt < S_; kt += 64) {
        const int ktB = kt + 32;
        const int ktA = (kt + 64 < S_) ? kt + 64 : 0;   // last prefetch harmless reload
        LOADK(b, ktB);       // prefetch next half-tile
        PROCESS(a, kt);
        LOADK(a, ktA);       // prefetch next tile
        PROCESS(b, ktB);
    }

#pragma unroll
    for (int dc = 0; dc < 4; ++dc)
#pragma unroll
        for (int r = 0; r < 4; ++r) {
            const int t = (b << 10) + q0 + fg * 4 + r;
            attn[(size_t)t * E_ + h * 64 + dc * 16 + fr] = (__half)(o[dc][r] / lrow[r]);
        }
}

// ---------------- per-token symmetric int8 requant (output as exact bf16) -------------
__global__ __launch_bounds__(256) void requant_kernel(
    const __half* __restrict__ attn, __bf16* __restrict__ aq, float* __restrict__ as_)
{
    const int t = blockIdx.x;
    const int tid = threadIdx.x;
    __shared__ float red[4];
    const __half* row = attn + (size_t)t * E_;
    float x[5];
    float amax = 0.f;
#pragma unroll
    for (int j = 0; j < 5; ++j) {
        x[j] = (float)row[tid + j * 256];
        amax = fmaxf(amax, fabsf(x[j]));
    }
#pragma unroll
    for (int off = 1; off < 64; off <<= 1) amax = fmaxf(amax, __shfl_xor(amax, off));
    if ((tid & 63) == 0) red[tid >> 6] = amax;
    __syncthreads();
    amax = fmaxf(fmaxf(red[0], red[1]), fmaxf(red[2], red[3]));
    const float s = fmaxf(amax / 127.f, 1e-8f);
    if (tid == 0) as_[t] = s;
#pragma unroll
    for (int j = 0; j < 5; ++j) {
        float qv = fminf(fmaxf(rintf(x[j] / s), -127.f), 127.f);
        aq[(size_t)t * E_ + tid + j * 256] = (__bf16)qv;
    }
}

// ---------------- launch ----------------
extern "C" void kernel_launch(void* const* d_in, const int* in_sizes, int n_in,
                              void* d_out, int out_size, void* d_ws, size_t ws_size,
                              hipStream_t stream) {
    const int*   x_q         = (const int*)d_in[0];
    const float* in_scale    = (const float*)d_in[1];
    const int*   w_qkv       = (const int*)d_in[2];
    const float* w_qkv_scale = (const float*)d_in[3];
    const float* b_qkv       = (const float*)d_in[4];
    const int*   w_out       = (const int*)d_in[5];
    const float* w_out_scale = (const float*)d_in[6];
    const float* b_out       = (const float*)d_in[7];
    float* out = (float*)d_out;

    char* ws = (char*)d_ws;
    __bf16* x_bf    = (__bf16*)(ws);                    // 20971520 B
    __bf16* wqkv_bf = (__bf16*)(ws + 20971520);         //  9830400 B
    __bf16* wout_bf = (__bf16*)(ws + 30801920);         //  3276800 B (live till GEMM2)
    __half* qh_f    = (__half*)(ws + 34078720);         // 20971520 B [B,H,S,D]
    __half* ql_f    = (__half*)(ws + 55050240);         // 20971520 B
    __half* kh_f    = (__half*)(ws + 76021760);         // 20971520 B
    __half* kl_f    = (__half*)(ws + 96993280);         // 20971520 B
    __half* vt_f    = (__half*)(ws + 117964800);        // 20971520 B [B,H,D,S]
    __half* attn_f  = (__half*)(ws);                    // 20971520 B [T,E] (overlays x_bf)
    __bf16* aq_bf   = (__bf16*)(ws + 34078720);         // 20971520 B [T,E] (overlays qh)
    float*  a_s     = (float*) (ws + 20971520);         //    32768 B (overlays wqkv)

    cvt_kernel<<<(T_ * E_ / 4 + 255) / 256, 256, 0, stream>>>(x_q, x_bf, T_ * E_ / 4);
    cvt_kernel<<<(QKV_ * E_ / 4 + 255) / 256, 256, 0, stream>>>(w_qkv, wqkv_bf, QKV_ * E_ / 4);
    cvt_kernel<<<(E_ * E_ / 4 + 255) / 256, 256, 0, stream>>>(w_out, wout_bf, E_ * E_ / 4);

    gemm_kernel<<<(T_ / 128) * (QKV_ / 128), 256, 0, stream>>>(
        x_bf, wqkv_bf, T_, QKV_, E_, in_scale, w_qkv_scale, b_qkv, 0,
        qh_f, ql_f, kh_f, kl_f, vt_f, nullptr);

    attn_kernel<<<B_ * H_ * (S_ / 64), 256, 0, stream>>>(qh_f, ql_f, kh_f, kl_f, vt_f, attn_f);

    requant_kernel<<<T_, 256, 0, stream>>>(attn_f, aq_bf, a_s);

    gemm_kernel<<<(T_ / 128) * (E_ / 128), 256, 0, stream>>>(
        aq_bf, wout_bf, T_, E_, E_, a_s, w_out_scale, b_out, 1,
        nullptr, nullptr, nullptr, nullptr, nullptr, out);
}

// Round 5
// 399.363 us; speedup vs baseline: 1.6754x; 1.6297x over previous
//
#include <hip/hip_runtime.h>
#include <hip/hip_bf16.h>
#include <hip/hip_fp16.h>

typedef __attribute__((ext_vector_type(4))) float f32x4;
typedef __attribute__((ext_vector_type(8))) __bf16 bf16x8;
typedef __attribute__((ext_vector_type(4))) __bf16 bf16x4;
typedef __attribute__((ext_vector_type(8))) _Float16 f16x8;
typedef __attribute__((ext_vector_type(4))) _Float16 f16x4;
typedef __attribute__((ext_vector_type(4))) int i32x4;

#define B_   8
#define S_   1024
#define H_   20
#define D_   64
#define E_   1280
#define QKV_ 3840
#define T_   8192

#define EXP2F(x) __builtin_amdgcn_exp2f(x)
#define QSCL 0.1803368801111204f   /* 0.125 * log2(e) */

__device__ __forceinline__ void gload_lds16(const void* g, void* l) {
    __builtin_amdgcn_global_load_lds((const __attribute__((address_space(1))) int*)g,
                                     (__attribute__((address_space(3))) int*)l, 16, 0, 0);
}

// ---------------- int32 -> bf16 convert (values in [-127,127], exact) ----------------
__global__ __launch_bounds__(256) void cvt_kernel(const int* __restrict__ in,
                                                  __bf16* __restrict__ out, int n4) {
    int i = blockIdx.x * 256 + threadIdx.x;
    if (i >= n4) return;
    i32x4 v = ((const i32x4*)in)[i];
    bf16x4 o;
    o[0] = (__bf16)(float)v[0];
    o[1] = (__bf16)(float)v[1];
    o[2] = (__bf16)(float)v[2];
    o[3] = (__bf16)(float)v[3];
    ((bf16x4*)out)[i] = o;
}

// ---------------- bf16 GEMM: C[M,N] = A[M,K] * B[N,K]^T, fused dequant epilogue -------
__global__ __launch_bounds__(256) void gemm_kernel(
    const __bf16* __restrict__ A, const __bf16* __restrict__ Bw,
    int M, int N, int K,
    const float* __restrict__ rowscale, const float* __restrict__ colscale,
    const float* __restrict__ bias, int epilogue,
    __half* __restrict__ qh_out, __half* __restrict__ ql_out,
    __half* __restrict__ kh_out, __half* __restrict__ kl_out,
    __half* __restrict__ vt_out, float* __restrict__ out)
{
    __shared__ __bf16 As[128 * 32];
    __shared__ __bf16 Bs[128 * 32];

    const int tid  = threadIdx.x;
    const int lane = tid & 63;
    const int wave = tid >> 6;
    const int wm = wave >> 1, wn = wave & 1;          // 2x2 waves of 64x64
    const int nTn = N >> 7;
    const int tm = blockIdx.x / nTn, tn = blockIdx.x % nTn;

    f32x4 acc[4][4] = {};

    const int r0 = tid >> 2;                // staging row
    const int ks = (tid & 3) * 8;           // staging k-offset (8 bf16 = 16B)
    const size_t abase = (size_t)tm * 128 * K;
    const size_t bbase = (size_t)tn * 128 * K;

    const int fr = lane & 15;
    const int fc = (lane >> 4) * 8;

    for (int k0 = 0; k0 < K; k0 += 32) {
        __syncthreads();
        gload_lds16(&A [abase + (size_t)r0        * K + k0 + ks], &As[(size_t)tid * 8]);
        gload_lds16(&A [abase + (size_t)(r0 + 64) * K + k0 + ks], &As[(size_t)(tid + 256) * 8]);
        gload_lds16(&Bw[bbase + (size_t)r0        * K + k0 + ks], &Bs[(size_t)tid * 8]);
        gload_lds16(&Bw[bbase + (size_t)(r0 + 64) * K + k0 + ks], &Bs[(size_t)(tid + 256) * 8]);
        __syncthreads();

        bf16x8 af[4], bf[4];
#pragma unroll
        for (int m = 0; m < 4; ++m)
            af[m] = *(const bf16x8*)&As[(wm * 64 + m * 16 + fr) * 32 + fc];
#pragma unroll
        for (int n = 0; n < 4; ++n)
            bf[n] = *(const bf16x8*)&Bs[(wn * 64 + n * 16 + fr) * 32 + fc];
        __builtin_amdgcn_s_setprio(1);
#pragma unroll
        for (int m = 0; m < 4; ++m)
#pragma unroll
            for (int n = 0; n < 4; ++n)
                acc[m][n] = __builtin_amdgcn_mfma_f32_16x16x32_bf16(af[m], bf[n], acc[m][n], 0, 0, 0);
        __builtin_amdgcn_s_setprio(0);
    }

#pragma unroll
    for (int m = 0; m < 4; ++m) {
#pragma unroll
        for (int r = 0; r < 4; ++r) {
            const int grow = tm * 128 + wm * 64 + m * 16 + (lane >> 4) * 4 + r;
            const float rs = rowscale[grow];
#pragma unroll
            for (int n = 0; n < 4; ++n) {
                const int gcol = tn * 128 + wn * 64 + n * 16 + (lane & 15);
                const float v = acc[m][n][r] * (rs * colscale[gcol]) + bias[gcol];
                if (epilogue == 0) {
                    const int b = grow >> 10, s = grow & 1023;
                    if (gcol < E_) {
                        // q: fold softmax scale (0.125*log2e), then split hi/lo
                        const float vq = v * QSCL;
                        const __half vh = (__half)vq;
                        const __half vl = (__half)(vq - (float)vh);
                        const int h = gcol >> 6, d = gcol & 63;
                        const size_t idx = (((size_t)(b * H_ + h) << 10) + s) * 64 + d;
                        qh_out[idx] = vh; ql_out[idx] = vl;
                    } else if (gcol < 2 * E_) {
                        const __half vh = (__half)v;
                        const __half vl = (__half)(v - (float)vh);
                        const int o = gcol - E_, h = o >> 6, d = o & 63;
                        const size_t idx = (((size_t)(b * H_ + h) << 10) + s) * 64 + d;
                        kh_out[idx] = vh; kl_out[idx] = vl;
                    } else {
                        const int o = gcol - 2 * E_, h = o >> 6, d = o & 63;
                        vt_out[(((size_t)(b * H_ + h) * 64 + d) << 10) + s] = (__half)v;
                    }
                } else {
                    out[(size_t)grow * E_ + gcol] = v;
                }
            }
        }
    }
}

// ---------------- flash attention v2: swapped QK^T, LDS-shared K, KVBLK=64 ----------
// grid: 2560 blocks (XCD-clustered remap); 4 waves/block, each wave owns 16 q-rows.
__global__ __launch_bounds__(256) void attn_kernel(
    const __half* __restrict__ Qh, const __half* __restrict__ Ql,
    const __half* __restrict__ Kh, const __half* __restrict__ Kl,
    const __half* __restrict__ VT, __half* __restrict__ attn)
{
    __shared__ __half KhL[2][64 * 64];   // [buf][row*64 + col], XOR-swizzled cols
    __shared__ __half KlL[2][64 * 64];
    __shared__ __half Pl[4][16 * 72];    // per-wave P bounce, stride 72 halfs (16B-mult)

    const int tid = threadIdx.x, lane = tid & 63, wave = tid >> 6;
    // XCD-clustered bijective remap: xcd = L&7 gets 20 contiguous heads
    const int L = blockIdx.x;
    const int sIdx = L >> 3;
    const int bh = (L & 7) * 20 + (sIdx >> 4);
    const int qt = sIdx & 15;
    const int b = bh / H_, h = bh % H_;
    const int q0 = qt * 64 + wave * 16;
    const size_t base_sd = (size_t)bh * S_ * D_;
    const size_t base_ds = (size_t)bh * D_ * S_;
    const int fr = lane & 15, fg = lane >> 4;

    // Q B-frags (pre-scaled in GEMM epilogue): lane -> q-col = q0+fr, d = fg*8..+7 (+32)
    f16x8 qh0 = *(const f16x8*)&Qh[base_sd + (size_t)(q0 + fr) * 64 +      fg * 8];
    f16x8 qh1 = *(const f16x8*)&Qh[base_sd + (size_t)(q0 + fr) * 64 + 32 + fg * 8];
    f16x8 ql0 = *(const f16x8*)&Ql[base_sd + (size_t)(q0 + fr) * 64 +      fg * 8];
    f16x8 ql1 = *(const f16x8*)&Ql[base_sd + (size_t)(q0 + fr) * 64 + 32 + fg * 8];

    f32x4 o[4] = {};
    float mrow = -INFINITY, lrow = 0.f;   // per-lane: ONE q-row (q0 + fr)

    // stage K chunk kt into buf bf: wave covers 2KB x2 arrays; linear LDS dest,
    // inverse-swizzled global source (rule 21): src col = cb ^ ((row&7)<<4)
#define STAGEK(bf, kt) do {                                                   \
    _Pragma("unroll")                                                         \
    for (int c_ = 0; c_ < 2; ++c_) {                                          \
        const int qb_ = wave * 2048 + c_ * 1024 + lane * 16;                  \
        const int row_ = qb_ >> 7, cb_ = qb_ & 127;                           \
        const int scb_ = cb_ ^ ((row_ & 7) << 4);                             \
        gload_lds16((const char*)(Kh + base_sd) + (size_t)((kt) + row_) * 128 + scb_, \
                    (char*)&KhL[bf][0] + qb_);                                \
        gload_lds16((const char*)(Kl + base_sd) + (size_t)((kt) + row_) * 128 + scb_, \
                    (char*)&KlL[bf][0] + qb_);                                \
    }                                                                         \
} while (0)

    STAGEK(0, 0);
    __syncthreads();

    for (int it = 0; it < 16; ++it) {
        const int kt = it * 64;
        const int bf = it & 1;

        // VT loads early (global, L1-shared across waves), consumed by PV at end
        f16x8 vf[4][2];
#pragma unroll
        for (int dc = 0; dc < 4; ++dc) {
            const size_t vb = base_ds + (size_t)(dc * 16 + fr) * S_ + kt + fg * 8;
            vf[dc][0] = *(const f16x8*)&VT[vb];
            vf[dc][1] = *(const f16x8*)&VT[vb + 32];
        }
        if (it < 15) STAGEK(bf ^ 1, kt + 64);

        // QK^T swapped: st[t] = S^T tile (16k x 16q); lane: q = q0+ (lane&15),
        // k = kt + t*16 + fg*4 + r
        f32x4 st[4] = {};
        __builtin_amdgcn_s_setprio(1);
#pragma unroll
        for (int t = 0; t < 4; ++t) {
            const int rowb = (t * 16 + fr) * 128;
            const int c0 = (fg * 16)      ^ ((fr & 7) << 4);
            const int c1 = (64 + fg * 16) ^ ((fr & 7) << 4);
            f16x8 a0 = *(const f16x8*)((const char*)&KhL[bf][0] + rowb + c0);
            f16x8 a1 = *(const f16x8*)((const char*)&KhL[bf][0] + rowb + c1);
            f16x8 e0 = *(const f16x8*)((const char*)&KlL[bf][0] + rowb + c0);
            f16x8 e1 = *(const f16x8*)((const char*)&KlL[bf][0] + rowb + c1);
            st[t] = __builtin_amdgcn_mfma_f32_16x16x32_f16(a0, qh0, st[t], 0, 0, 0);
            st[t] = __builtin_amdgcn_mfma_f32_16x16x32_f16(a1, qh1, st[t], 0, 0, 0);
            st[t] = __builtin_amdgcn_mfma_f32_16x16x32_f16(a0, ql0, st[t], 0, 0, 0);
            st[t] = __builtin_amdgcn_mfma_f32_16x16x32_f16(a1, ql1, st[t], 0, 0, 0);
            st[t] = __builtin_amdgcn_mfma_f32_16x16x32_f16(e0, qh0, st[t], 0, 0, 0);
            st[t] = __builtin_amdgcn_mfma_f32_16x16x32_f16(e1, qh1, st[t], 0, 0, 0);
        }
        __builtin_amdgcn_s_setprio(0);

        // softmax over 64 kv for this lane's q-row: in-lane 16 + xor16 + xor32
        float mt0 = fmaxf(fmaxf(st[0][0], st[0][1]), fmaxf(st[0][2], st[0][3]));
        float mt1 = fmaxf(fmaxf(st[1][0], st[1][1]), fmaxf(st[1][2], st[1][3]));
        float mt2 = fmaxf(fmaxf(st[2][0], st[2][1]), fmaxf(st[2][2], st[2][3]));
        float mt3 = fmaxf(fmaxf(st[3][0], st[3][1]), fmaxf(st[3][2], st[3][3]));
        float mx = fmaxf(fmaxf(mt0, mt1), fmaxf(mt2, mt3));
        mx = fmaxf(mx, __shfl_xor(mx, 16));
        mx = fmaxf(mx, __shfl_xor(mx, 32));
        const float mn = fmaxf(mrow, mx);
        const float fsc = EXP2F(mrow - mn);
        mrow = mn;

        float p[4][4];
        float rs = 0.f;
#pragma unroll
        for (int t = 0; t < 4; ++t) {
            p[t][0] = EXP2F(st[t][0] - mn);
            p[t][1] = EXP2F(st[t][1] - mn);
            p[t][2] = EXP2F(st[t][2] - mn);
            p[t][3] = EXP2F(st[t][3] - mn);
            rs += (p[t][0] + p[t][1]) + (p[t][2] + p[t][3]);
        }
        rs += __shfl_xor(rs, 16);
        rs += __shfl_xor(rs, 32);
        lrow = lrow * fsc + rs;

        // broadcast fsc to o-accumulator rows (o rows are q = q0 + fg*4 + r)
        float fscr[4];
#pragma unroll
        for (int r = 0; r < 4; ++r) fscr[r] = __shfl(fsc, ((lane >> 4) << 2) + r);
#pragma unroll
        for (int dc = 0; dc < 4; ++dc)
#pragma unroll
            for (int r = 0; r < 4; ++r) o[dc][r] *= fscr[r];

        // P -> LDS (row q = fr, k = t*16 + fg*4 .. +3) as b64 writes
#pragma unroll
        for (int t = 0; t < 4; ++t) {
            f16x4 pk;
            pk[0] = (_Float16)p[t][0]; pk[1] = (_Float16)p[t][1];
            pk[2] = (_Float16)p[t][2]; pk[3] = (_Float16)p[t][3];
            *(f16x4*)((char*)&Pl[wave][0] + fr * 144 + t * 32 + fg * 8) = pk;
        }
        asm volatile("s_waitcnt lgkmcnt(0)" ::: "memory");
        __builtin_amdgcn_sched_barrier(0);
        f16x8 pf0 = *(const f16x8*)((const char*)&Pl[wave][0] + fr * 144 +      fg * 16);
        f16x8 pf1 = *(const f16x8*)((const char*)&Pl[wave][0] + fr * 144 + 64 + fg * 16);
        __builtin_amdgcn_s_setprio(1);
#pragma unroll
        for (int dc = 0; dc < 4; ++dc) {
            o[dc] = __builtin_amdgcn_mfma_f32_16x16x32_f16(pf0, vf[dc][0], o[dc], 0, 0, 0);
            o[dc] = __builtin_amdgcn_mfma_f32_16x16x32_f16(pf1, vf[dc][1], o[dc], 0, 0, 0);
        }
        __builtin_amdgcn_s_setprio(0);
        __syncthreads();   // buf consumed by all waves + next staging drained
    }

    float lrowr[4];
#pragma unroll
    for (int r = 0; r < 4; ++r) lrowr[r] = __shfl(lrow, ((lane >> 4) << 2) + r);
#pragma unroll
    for (int dc = 0; dc < 4; ++dc)
#pragma unroll
        for (int r = 0; r < 4; ++r) {
            const int t = (b << 10) + q0 + fg * 4 + r;
            attn[(size_t)t * E_ + h * 64 + dc * 16 + fr] = (__half)(o[dc][r] / lrowr[r]);
        }
#undef STAGEK
}

// ---------------- per-token symmetric int8 requant (output as exact bf16) -------------
__global__ __launch_bounds__(256) void requant_kernel(
    const __half* __restrict__ attn, __bf16* __restrict__ aq, float* __restrict__ as_)
{
    const int t = blockIdx.x;
    const int tid = threadIdx.x;
    __shared__ float red[4];
    const __half* row = attn + (size_t)t * E_;
    float x[5];
    float amax = 0.f;
#pragma unroll
    for (int j = 0; j < 5; ++j) {
        x[j] = (float)row[tid + j * 256];
        amax = fmaxf(amax, fabsf(x[j]));
    }
#pragma unroll
    for (int off = 1; off < 64; off <<= 1) amax = fmaxf(amax, __shfl_xor(amax, off));
    if ((tid & 63) == 0) red[tid >> 6] = amax;
    __syncthreads();
    amax = fmaxf(fmaxf(red[0], red[1]), fmaxf(red[2], red[3]));
    const float s = fmaxf(amax / 127.f, 1e-8f);
    if (tid == 0) as_[t] = s;
#pragma unroll
    for (int j = 0; j < 5; ++j) {
        float qv = fminf(fmaxf(rintf(x[j] / s), -127.f), 127.f);
        aq[(size_t)t * E_ + tid + j * 256] = (__bf16)qv;
    }
}

// ---------------- launch ----------------
extern "C" void kernel_launch(void* const* d_in, const int* in_sizes, int n_in,
                              void* d_out, int out_size, void* d_ws, size_t ws_size,
                              hipStream_t stream) {
    const int*   x_q         = (const int*)d_in[0];
    const float* in_scale    = (const float*)d_in[1];
    const int*   w_qkv       = (const int*)d_in[2];
    const float* w_qkv_scale = (const float*)d_in[3];
    const float* b_qkv       = (const float*)d_in[4];
    const int*   w_out       = (const int*)d_in[5];
    const float* w_out_scale = (const float*)d_in[6];
    const float* b_out       = (const float*)d_in[7];
    float* out = (float*)d_out;

    char* ws = (char*)d_ws;
    __bf16* x_bf    = (__bf16*)(ws);                    // 20971520 B
    __bf16* wqkv_bf = (__bf16*)(ws + 20971520);         //  9830400 B
    __bf16* wout_bf = (__bf16*)(ws + 30801920);         //  3276800 B (live till GEMM2)
    __half* qh_f    = (__half*)(ws + 34078720);         // 20971520 B [B,H,S,D]
    __half* ql_f    = (__half*)(ws + 55050240);         // 20971520 B
    __half* kh_f    = (__half*)(ws + 76021760);         // 20971520 B
    __half* kl_f    = (__half*)(ws + 96993280);         // 20971520 B
    __half* vt_f    = (__half*)(ws + 117964800);        // 20971520 B [B,H,D,S]
    __half* attn_f  = (__half*)(ws);                    // 20971520 B [T,E] (overlays x_bf)
    __bf16* aq_bf   = (__bf16*)(ws + 34078720);         // 20971520 B [T,E] (overlays qh)
    float*  a_s     = (float*) (ws + 20971520);         //    32768 B (overlays wqkv)

    cvt_kernel<<<(T_ * E_ / 4 + 255) / 256, 256, 0, stream>>>(x_q, x_bf, T_ * E_ / 4);
    cvt_kernel<<<(QKV_ * E_ / 4 + 255) / 256, 256, 0, stream>>>(w_qkv, wqkv_bf, QKV_ * E_ / 4);
    cvt_kernel<<<(E_ * E_ / 4 + 255) / 256, 256, 0, stream>>>(w_out, wout_bf, E_ * E_ / 4);

    gemm_kernel<<<(T_ / 128) * (QKV_ / 128), 256, 0, stream>>>(
        x_bf, wqkv_bf, T_, QKV_, E_, in_scale, w_qkv_scale, b_qkv, 0,
        qh_f, ql_f, kh_f, kl_f, vt_f, nullptr);

    attn_kernel<<<B_ * H_ * (S_ / 64), 256, 0, stream>>>(qh_f, ql_f, kh_f, kl_f, vt_f, attn_f);

    requant_kernel<<<T_, 256, 0, stream>>>(attn_f, aq_bf, a_s);

    gemm_kernel<<<(T_ / 128) * (E_ / 128), 256, 0, stream>>>(
        aq_bf, wout_bf, T_, E_, E_, a_s, w_out_scale, b_out, 1,
        nullptr, nullptr, nullptr, nullptr, nullptr, out);
}